// Round 5
// baseline (1607.361 us; speedup 1.0000x reference)
//
#include <hip/hip_runtime.h>
#include <hip/hip_bf16.h>
#include <math.h>

#define NEG_SLOPE 0.2f
typedef __hip_bfloat16 bf16;
typedef __attribute__((ext_vector_type(8))) unsigned short ushort8;

// XOR swizzle: logical float-column c -> physical column (breaks stride-32 conflicts)
#define SWZ(c) ((c) ^ ((((c) >> 5) & 7) << 2))

__device__ __forceinline__ float bf2f(unsigned short u) {
    return __uint_as_float(((unsigned)u) << 16);
}

__device__ __forceinline__ void edge_sd(const int* __restrict__ ei, int E, int e, int& s, int& d) {
    if (e < E) { s = ei[e]; d = ei[E + e]; }
    else { s = e - E; d = s; }  // self-loop
}

// ================= CSR build =================
__global__ void k_hist(const int* __restrict__ ei, int E, int Etot, int* __restrict__ deg)
{
    int e = blockIdx.x * blockDim.x + threadIdx.x;
    if (e >= Etot) return;
    int s, d; edge_sd(ei, E, e, s, d);
    atomicAdd(&deg[d], 1);
}

__global__ __launch_bounds__(1024) void k_scan(const int* __restrict__ deg,
                                               int* __restrict__ rs, int N)
{
    __shared__ int part[1024];
    int t = threadIdx.x;
    int chunk = (N + 1023) >> 10;
    int b = t * chunk, e = min(b + chunk, N);
    int s = 0;
    for (int i = b; i < e; ++i) s += deg[i];
    part[t] = s;
    __syncthreads();
    for (int off = 1; off < 1024; off <<= 1) {
        int v = (t >= off) ? part[t - off] : 0;
        __syncthreads();
        part[t] += v;
        __syncthreads();
    }
    int excl = (t == 0) ? 0 : part[t - 1];
    for (int i = b; i < e; ++i) { rs[i] = excl; excl += deg[i]; }
    if (t == 1023) rs[N] = part[1023];
}

__global__ void k_fill(const int* __restrict__ ei, int E, int Etot,
                       const int* __restrict__ rs, int* __restrict__ cur,
                       int* __restrict__ csr_src)
{
    int e = blockIdx.x * blockDim.x + threadIdx.x;
    if (e >= Etot) return;
    int s, d; edge_sd(ei, E, e, s, d);
    int pos = rs[d] + atomicAdd(&cur[d], 1);
    csr_src[pos] = s;
}

// ================= Layer 1 =================
// wboth[k][c16]: c<8 -> src-fold head c ; c>=8 -> dst-fold head c-8
__global__ __launch_bounds__(512) void k_prew(
    const float* __restrict__ W1, const float* __restrict__ a_src,
    const float* __restrict__ a_dst, float* __restrict__ wboth)
{
    int t = threadIdx.x;           // 512 = 64 k x 8 h
    int k = t >> 3, h = t & 7;
    float s = 0.f, d = 0.f;
    const float* wr = W1 + k * 512 + h * 64;
    const float* as = a_src + h * 64;
    const float* ad = a_dst + h * 64;
#pragma unroll
    for (int c = 0; c < 64; ++c) { s += wr[c] * as[c]; d += wr[c] * ad[c]; }
    wboth[k * 16 + h] = s;
    wboth[k * 16 + 8 + h] = d;
}

// per-node attention terms: 256 thr = 4 waves x 4 nodes x 16 lanes
__global__ __launch_bounds__(256) void k_alpha1n(
    const float* __restrict__ x, const float* __restrict__ wboth,
    float* __restrict__ asrc, float* __restrict__ adst, int N)
{
    __shared__ float wl[16][64];   // transposed: wl[c][k]
    int t = threadIdx.x;
    for (int i = t; i < 1024; i += 256) {
        int k = i >> 4, c = i & 15;
        wl[c][k] = wboth[i];
    }
    __syncthreads();
    int wave = t >> 6, lane = t & 63;
    int nsub = lane >> 4, ksub = lane & 15;
    int n = blockIdx.x * 16 + wave * 4 + nsub;
    bool valid = (n < N);
    float xv[4];
#pragma unroll
    for (int i = 0; i < 4; ++i)
        xv[i] = valid ? x[(size_t)n * 64 + i * 16 + ksub] : 0.f;
    float acc[16];
#pragma unroll
    for (int c = 0; c < 16; ++c) acc[c] = 0.f;
#pragma unroll
    for (int i = 0; i < 4; ++i) {
        float xi = xv[i];
        int k = i * 16 + ksub;
#pragma unroll
        for (int c = 0; c < 16; ++c) acc[c] += xi * wl[c][k];
    }
#pragma unroll
    for (int c = 0; c < 16; ++c) {
        acc[c] += __shfl_xor(acc[c], 1, 16);
        acc[c] += __shfl_xor(acc[c], 2, 16);
        acc[c] += __shfl_xor(acc[c], 4, 16);
        acc[c] += __shfl_xor(acc[c], 8, 16);
    }
    if (valid) {
        if (ksub < 8) asrc[n * 8 + ksub] = acc[ksub];
        else          adst[n * 8 + (ksub - 8)] = acc[ksub];
    }
}

// softmax layer1: wave per node; lane = (j0 = lane>>3, head = lane&7)
__global__ __launch_bounds__(256) void k_sm1(
    const int* __restrict__ rs, const int* __restrict__ csr_src,
    const float* __restrict__ asrc, const float* __restrict__ adst,
    float* __restrict__ aE, int N)
{
    int node = blockIdx.x * 4 + (threadIdx.x >> 6);
    if (node >= N) return;
    int lane = threadIdx.x & 63;
    int h = lane & 7, j0 = lane >> 3;
    int base = rs[node], deg = rs[node + 1] - base;
    float ad = adst[node * 8 + h];
    float m = -1e30f;
    for (int j = j0; j < deg; j += 8) {
        int s = csr_src[base + j];
        float el = asrc[s * 8 + h] + ad;
        el = el >= 0.f ? el : NEG_SLOPE * el;
        m = fmaxf(m, el);
    }
    m = fmaxf(m, __shfl_xor(m, 8, 64));
    m = fmaxf(m, __shfl_xor(m, 16, 64));
    m = fmaxf(m, __shfl_xor(m, 32, 64));
    float sum = 0.f;
    for (int j = j0; j < deg; j += 8) {
        int s = csr_src[base + j];
        float el = asrc[s * 8 + h] + ad;
        el = el >= 0.f ? el : NEG_SLOPE * el;
        float p = expf(el - m);
        sum += p;
        aE[(size_t)(base + j) * 8 + h] = p;
    }
    sum += __shfl_xor(sum, 8, 64);
    sum += __shfl_xor(sum, 16, 64);
    sum += __shfl_xor(sum, 32, 64);
    float inv = 1.f / (sum + 1e-16f);
    for (int j = j0; j < deg; j += 8) aE[(size_t)(base + j) * 8 + h] *= inv;
}

// aggregate in x-space: z[d][h][k] = sum_j alpha[j,h] * x[src_j][k]
__global__ __launch_bounds__(512) void k_aggx(
    const int* __restrict__ rs, const int* __restrict__ csr_src,
    const float* __restrict__ aE, const float* __restrict__ x,
    bf16* __restrict__ z, int N)
{
    int d = blockIdx.x;
    int t = threadIdx.x;
    int h = t >> 6, k = t & 63;
    int base = rs[d], end = rs[d + 1];
    float acc = 0.f;
    int p = base;
    for (; p + 3 < end; p += 4) {
        int s0 = csr_src[p],     s1 = csr_src[p + 1];
        int s2 = csr_src[p + 2], s3 = csr_src[p + 3];
        float a0 = aE[(size_t)p * 8 + h];
        float a1 = aE[(size_t)(p + 1) * 8 + h];
        float a2 = aE[(size_t)(p + 2) * 8 + h];
        float a3 = aE[(size_t)(p + 3) * 8 + h];
        float x0 = x[(size_t)s0 * 64 + k];
        float x1 = x[(size_t)s1 * 64 + k];
        float x2 = x[(size_t)s2 * 64 + k];
        float x3 = x[(size_t)s3 * 64 + k];
        acc += a0 * x0 + a1 * x1 + a2 * x2 + a3 * x3;
    }
    for (; p < end; ++p) {
        int s0 = csr_src[p];
        acc += aE[(size_t)p * 8 + h] * x[(size_t)s0 * 64 + k];
    }
    z[(size_t)d * 512 + t] = __float2bfloat16(acc);
}

// per-head GEMM: y[n, h*64+c2] = elu( sum_k z[n][h][k] * W1[k][h*64+c2] + b1 )
// 16-wide W1 k-tile in registers; z read as broadcast float4 (b128) from LDS.
#define NPB 8
__global__ __launch_bounds__(512) void k_gemmz(
    const bf16* __restrict__ z, const float* __restrict__ W1,
    const float* __restrict__ b1, bf16* __restrict__ y, int N)
{
    int n0 = blockIdx.x * NPB;
    int t = threadIdx.x;
    __shared__ float zs[NPB][512];
    {
        int e = t * 8;
        int m = e >> 9, col = e & 511;
        int n = n0 + m;
        if (n < N) {
            ushort8 u = *(const ushort8*)(z + (size_t)n * 512 + col);
#pragma unroll
            for (int j = 0; j < 8; ++j) zs[m][col + j] = bf2f(u[j]);
        } else {
#pragma unroll
            for (int j = 0; j < 8; ++j) zs[m][col + j] = 0.f;
        }
    }
    __syncthreads();
    int h = t >> 6;
    float acc[NPB];
#pragma unroll
    for (int m = 0; m < NPB; ++m) acc[m] = 0.f;
    const float* wcol = W1 + t;
#pragma unroll
    for (int tile = 0; tile < 4; ++tile) {
        float w[16];
#pragma unroll
        for (int j = 0; j < 16; ++j) w[j] = wcol[(size_t)(tile * 16 + j) * 512];
#pragma unroll
        for (int m = 0; m < NPB; ++m) {
            const float4* zp = (const float4*)&zs[m][h * 64 + tile * 16];
            float4 z0 = zp[0], z1 = zp[1], z2 = zp[2], z3 = zp[3];
            acc[m] += z0.x * w[0]  + z0.y * w[1]  + z0.z * w[2]  + z0.w * w[3]
                    + z1.x * w[4]  + z1.y * w[5]  + z1.z * w[6]  + z1.w * w[7]
                    + z2.x * w[8]  + z2.y * w[9]  + z2.z * w[10] + z2.w * w[11]
                    + z3.x * w[12] + z3.y * w[13] + z3.z * w[14] + z3.w * w[15];
        }
    }
    float bias = b1[t];
#pragma unroll
    for (int m = 0; m < NPB; ++m) {
        int n = n0 + m;
        if (n < N) {
            float v = acc[m] + bias;
            v = v > 0.f ? v : expf(v) - 1.f;
            y[(size_t)n * 512 + t] = __float2bfloat16(v);
        }
    }
}

// ================= Layer 2 =================
// h2 = y @ W2 (+ fused attention dots). 512 thr = 8 waves x 4 nodes x 16 lanes.
// 64 nodes per block (2 passes) to amortize W2 staging; W2t XOR-swizzled.
__global__ __launch_bounds__(512) void k_gemm2(
    const bf16* __restrict__ y, const float* __restrict__ W2,
    const float* __restrict__ a_src2, const float* __restrict__ a_dst2,
    float* __restrict__ h2, float* __restrict__ asrc, float* __restrict__ adst, int N)
{
    __shared__ float W2t[17][512];
    __shared__ float a2s[34];
    int t = threadIdx.x;
    for (int i = t; i < 17 * 512; i += 512) {
        int c = i >> 9, k = i & 511;
        W2t[c][SWZ(k)] = W2[k * 17 + c];
    }
    if (t < 17) a2s[t] = a_src2[t];
    else if (t < 34) a2s[t] = a_dst2[t - 17];
    __syncthreads();

    int wave = t >> 6, lane = t & 63;
    int nsub = lane >> 4, ksub = lane & 15;
    int kx = ksub & 7;

#pragma unroll
    for (int pass = 0; pass < 2; ++pass) {
        int n = blockIdx.x * 64 + pass * 32 + wave * 4 + nsub;
        bool valid = (n < N);

        float yk[32];
        if (valid) {
            const ushort8* yr = (const ushort8*)(y + (size_t)n * 512 + ksub * 32);
#pragma unroll
            for (int v = 0; v < 4; ++v) {
                ushort8 u = yr[v];
#pragma unroll
                for (int j = 0; j < 8; ++j) yk[v * 8 + j] = bf2f(u[j]);
            }
        } else {
#pragma unroll
            for (int i = 0; i < 32; ++i) yk[i] = 0.f;
        }

        float acc[17];
#pragma unroll
        for (int c = 0; c < 17; ++c) {
            float a = 0.f;
#pragma unroll
            for (int v = 0; v < 8; ++v) {
                // physical chunk (v ^ kx) holds logical k-chunk v
                const float4 w = *(const float4*)&W2t[c][ksub * 32 + ((v ^ kx) << 2)];
                a += yk[v * 4 + 0] * w.x + yk[v * 4 + 1] * w.y
                   + yk[v * 4 + 2] * w.z + yk[v * 4 + 3] * w.w;
            }
            acc[c] = a;
        }
#pragma unroll
        for (int c = 0; c < 17; ++c) {
            acc[c] += __shfl_xor(acc[c], 1, 16);
            acc[c] += __shfl_xor(acc[c], 2, 16);
            acc[c] += __shfl_xor(acc[c], 4, 16);
            acc[c] += __shfl_xor(acc[c], 8, 16);
        }
        if (valid) {
            if (ksub < 16) h2[(size_t)n * 17 + ksub] = acc[ksub];
            if (ksub == 0) h2[(size_t)n * 17 + 16] = acc[16];
            if (ksub == 1) {
                float s = 0.f;
#pragma unroll
                for (int c = 0; c < 17; ++c) s += acc[c] * a2s[c];
                asrc[n] = s;
            }
            if (ksub == 2) {
                float d = 0.f;
#pragma unroll
                for (int c = 0; c < 17; ++c) d += acc[c] * a2s[17 + c];
                adst[n] = d;
            }
        }
    }
}

// softmax layer2: wave per node, lane = edge slot
__global__ __launch_bounds__(256) void k_sm2(
    const int* __restrict__ rs, const int* __restrict__ csr_src,
    const float* __restrict__ asrc, const float* __restrict__ adst,
    float* __restrict__ alpha, int N)
{
    int node = blockIdx.x * 4 + (threadIdx.x >> 6);
    if (node >= N) return;
    int lane = threadIdx.x & 63;
    int base = rs[node], deg = rs[node + 1] - base;
    float ad = adst[node];
    float m = -1e30f;
    for (int j = lane; j < deg; j += 64) {
        float el = asrc[csr_src[base + j]] + ad;
        el = el >= 0.f ? el : NEG_SLOPE * el;
        m = fmaxf(m, el);
    }
#pragma unroll
    for (int off = 1; off < 64; off <<= 1) m = fmaxf(m, __shfl_xor(m, off, 64));
    float sum = 0.f;
    for (int j = lane; j < deg; j += 64) {
        float el = asrc[csr_src[base + j]] + ad;
        el = el >= 0.f ? el : NEG_SLOPE * el;
        float p = expf(el - m);
        sum += p;
        alpha[base + j] = p;
    }
#pragma unroll
    for (int off = 1; off < 64; off <<= 1) sum += __shfl_xor(sum, off, 64);
    float inv = 1.f / (sum + 1e-16f);
    for (int j = lane; j < deg; j += 64) alpha[base + j] *= inv;
}

// aggregate layer2 + bias + log_softmax: wave per node; lane = (jsub = lane>>5, c = lane&31)
__global__ __launch_bounds__(256) void k_out(
    const int* __restrict__ rs, const int* __restrict__ csr_src,
    const float* __restrict__ alpha, const float* __restrict__ h2,
    const float* __restrict__ b2, float* __restrict__ out, int N)
{
    int node = blockIdx.x * 4 + (threadIdx.x >> 6);
    if (node >= N) return;
    int lane = threadIdx.x & 63;
    int c = lane & 31, jsub = lane >> 5;
    int base = rs[node], end = rs[node + 1];
    float acc = 0.f;
    if (c < 17) {
        for (int p = base + jsub; p < end; p += 2) {
            int s = csr_src[p];
            acc += alpha[p] * h2[(size_t)s * 17 + c];
        }
    }
    acc += __shfl_xor(acc, 32, 64);  // combine the two edge halves
    float logit = (c < 17) ? acc + b2[c] : -1e30f;
    float m = logit;
#pragma unroll
    for (int off = 1; off < 32; off <<= 1) m = fmaxf(m, __shfl_xor(m, off, 32));
    float p = (c < 17) ? expf(logit - m) : 0.f;
    float ssum = p;
#pragma unroll
    for (int off = 1; off < 32; off <<= 1) ssum += __shfl_xor(ssum, off, 32);
    if (c < 17 && jsub == 0) out[(size_t)node * 17 + c] = logit - m - logf(ssum);
}

extern "C" void kernel_launch(void* const* d_in, const int* in_sizes, int n_in,
                              void* d_out, int out_size, void* d_ws, size_t ws_size,
                              hipStream_t stream)
{
    const float* x      = (const float*)d_in[0];
    const int*   ei     = (const int*)d_in[1];
    const float* W1     = (const float*)d_in[2];
    const float* asrc1w = (const float*)d_in[3];
    const float* adst1w = (const float*)d_in[4];
    const float* b1     = (const float*)d_in[5];
    const float* W2     = (const float*)d_in[6];
    const float* asrc2w = (const float*)d_in[7];
    const float* adst2w = (const float*)d_in[8];
    const float* b2     = (const float*)d_in[9];
    float* out = (float*)d_out;

    const int N = in_sizes[0] / 64;
    const int E = in_sizes[1] / 2;
    const int Etot = N + E;

    // workspace layout
    float* ws = (float*)d_ws;
    size_t o = 0;
    bf16*  z     = (bf16*)(ws + o); o += (size_t)N * 256;   // N*512 bf16
    bf16*  y     = (bf16*)(ws + o); o += (size_t)N * 256;   // N*512 bf16
    float* wboth = ws + o; o += 1024;
    float* asrc1 = ws + o; o += (size_t)N * 8;
    float* adst1 = ws + o; o += (size_t)N * 8;
    float* aE1   = ws + o; o += (size_t)Etot * 8;
    float* h2    = ws + o; o += (size_t)N * 17;
    float* asrc2 = ws + o; o += (size_t)N;
    float* adst2 = ws + o; o += (size_t)N;
    float* aE2   = ws + o; o += (size_t)Etot;
    int* deg     = (int*)(ws + o); o += (size_t)N;
    int* cur     = (int*)(ws + o); o += (size_t)N;
    int* rs      = (int*)(ws + o); o += (size_t)N + 1;
    int* csr_src = (int*)(ws + o); o += (size_t)Etot;

    hipMemsetAsync(deg, 0, (size_t)N * 4, stream);
    hipMemsetAsync(cur, 0, (size_t)N * 4, stream);

    // CSR build
    {
        int blk = 256, g = (Etot + blk - 1) / blk;
        k_hist<<<g, blk, 0, stream>>>(ei, E, Etot, deg);
        k_scan<<<1, 1024, 0, stream>>>(deg, rs, N);
        k_fill<<<g, blk, 0, stream>>>(ei, E, Etot, rs, cur, csr_src);
    }

    // layer 1
    k_prew<<<1, 512, 0, stream>>>(W1, asrc1w, adst1w, wboth);
    k_alpha1n<<<(N + 15) / 16, 256, 0, stream>>>(x, wboth, asrc1, adst1, N);
    k_sm1<<<(N + 3) / 4, 256, 0, stream>>>(rs, csr_src, asrc1, adst1, aE1, N);
    k_aggx<<<N, 512, 0, stream>>>(rs, csr_src, aE1, x, z, N);
    k_gemmz<<<(N + NPB - 1) / NPB, 512, 0, stream>>>(z, W1, b1, y, N);

    // layer 2
    k_gemm2<<<(N + 63) / 64, 512, 0, stream>>>(y, W2, asrc2w, adst2w, h2, asrc2, adst2, N);
    k_sm2<<<(N + 3) / 4, 256, 0, stream>>>(rs, csr_src, asrc2, adst2, aE2, N);
    k_out<<<(N + 3) / 4, 256, 0, stream>>>(rs, csr_src, aE2, h2, b2, out, N);
}

// Round 6
// 513.026 us; speedup vs baseline: 3.1331x; 3.1331x over previous
//
#include <hip/hip_runtime.h>
#include <hip/hip_bf16.h>
#include <math.h>

#define NEG_SLOPE 0.2f
typedef __hip_bfloat16 bf16;
typedef __attribute__((ext_vector_type(8))) unsigned short ushort8;

// XOR swizzle: logical float-column c -> physical column (breaks stride-32 conflicts)
#define SWZ(c) ((c) ^ ((((c) >> 5) & 7) << 2))

__device__ __forceinline__ float bf2f(unsigned short u) {
    return __uint_as_float(((unsigned)u) << 16);
}

__device__ __forceinline__ void edge_sd(const int* __restrict__ ei, int E, int e, int& s, int& d) {
    if (e < E) { s = ei[e]; d = ei[E + e]; }
    else { s = e - E; d = s; }  // self-loop
}

// ================= CSR build =================
__global__ void k_hist(const int* __restrict__ ei, int E, int Etot, int* __restrict__ deg)
{
    int e = blockIdx.x * blockDim.x + threadIdx.x;
    if (e >= Etot) return;
    int s, d; edge_sd(ei, E, e, s, d);
    atomicAdd(&deg[d], 1);
}

__global__ __launch_bounds__(1024) void k_scan(const int* __restrict__ deg,
                                               int* __restrict__ rs, int N)
{
    __shared__ int part[1024];
    int t = threadIdx.x;
    int chunk = (N + 1023) >> 10;
    int b = t * chunk, e = min(b + chunk, N);
    int s = 0;
    for (int i = b; i < e; ++i) s += deg[i];
    part[t] = s;
    __syncthreads();
    for (int off = 1; off < 1024; off <<= 1) {
        int v = (t >= off) ? part[t - off] : 0;
        __syncthreads();
        part[t] += v;
        __syncthreads();
    }
    int excl = (t == 0) ? 0 : part[t - 1];
    for (int i = b; i < e; ++i) { rs[i] = excl; excl += deg[i]; }
    if (t == 1023) rs[N] = part[1023];
}

__global__ void k_fill(const int* __restrict__ ei, int E, int Etot,
                       const int* __restrict__ rs, int* __restrict__ cur,
                       int* __restrict__ csr_src)
{
    int e = blockIdx.x * blockDim.x + threadIdx.x;
    if (e >= Etot) return;
    int s, d; edge_sd(ei, E, e, s, d);
    int pos = rs[d] + atomicAdd(&cur[d], 1);
    csr_src[pos] = s;
}

// ================= Layer 1 =================
// wboth[k][c16]: c<8 -> src-fold head c ; c>=8 -> dst-fold head c-8
__global__ __launch_bounds__(512) void k_prew(
    const float* __restrict__ W1, const float* __restrict__ a_src,
    const float* __restrict__ a_dst, float* __restrict__ wboth)
{
    int t = threadIdx.x;           // 512 = 64 k x 8 h
    int k = t >> 3, h = t & 7;
    float s = 0.f, d = 0.f;
    const float* wr = W1 + k * 512 + h * 64;
    const float* as = a_src + h * 64;
    const float* ad = a_dst + h * 64;
#pragma unroll
    for (int c = 0; c < 64; ++c) { s += wr[c] * as[c]; d += wr[c] * ad[c]; }
    wboth[k * 16 + h] = s;
    wboth[k * 16 + 8 + h] = d;
}

// per-node attention terms: 256 thr = 4 waves x 4 nodes x 16 lanes
__global__ __launch_bounds__(256) void k_alpha1n(
    const float* __restrict__ x, const float* __restrict__ wboth,
    float* __restrict__ asrc, float* __restrict__ adst, int N)
{
    __shared__ float wl[16][64];   // transposed: wl[c][k]
    int t = threadIdx.x;
    for (int i = t; i < 1024; i += 256) {
        int k = i >> 4, c = i & 15;
        wl[c][k] = wboth[i];
    }
    __syncthreads();
    int wave = t >> 6, lane = t & 63;
    int nsub = lane >> 4, ksub = lane & 15;
    int n = blockIdx.x * 16 + wave * 4 + nsub;
    bool valid = (n < N);
    float xv[4];
#pragma unroll
    for (int i = 0; i < 4; ++i)
        xv[i] = valid ? x[(size_t)n * 64 + i * 16 + ksub] : 0.f;
    float acc[16];
#pragma unroll
    for (int c = 0; c < 16; ++c) acc[c] = 0.f;
#pragma unroll
    for (int i = 0; i < 4; ++i) {
        float xi = xv[i];
        int k = i * 16 + ksub;
#pragma unroll
        for (int c = 0; c < 16; ++c) acc[c] += xi * wl[c][k];
    }
#pragma unroll
    for (int c = 0; c < 16; ++c) {
        acc[c] += __shfl_xor(acc[c], 1, 16);
        acc[c] += __shfl_xor(acc[c], 2, 16);
        acc[c] += __shfl_xor(acc[c], 4, 16);
        acc[c] += __shfl_xor(acc[c], 8, 16);
    }
    if (valid) {
        if (ksub < 8) asrc[n * 8 + ksub] = acc[ksub];
        else          adst[n * 8 + (ksub - 8)] = acc[ksub];
    }
}

// softmax layer1: wave per node; lane = (j0 = lane>>3, head = lane&7)
__global__ __launch_bounds__(256) void k_sm1(
    const int* __restrict__ rs, const int* __restrict__ csr_src,
    const float* __restrict__ asrc, const float* __restrict__ adst,
    float* __restrict__ aE, int N)
{
    int node = blockIdx.x * 4 + (threadIdx.x >> 6);
    if (node >= N) return;
    int lane = threadIdx.x & 63;
    int h = lane & 7, j0 = lane >> 3;
    int base = rs[node], deg = rs[node + 1] - base;
    float ad = adst[node * 8 + h];
    float m = -1e30f;
    for (int j = j0; j < deg; j += 8) {
        int s = csr_src[base + j];
        float el = asrc[s * 8 + h] + ad;
        el = el >= 0.f ? el : NEG_SLOPE * el;
        m = fmaxf(m, el);
    }
    m = fmaxf(m, __shfl_xor(m, 8, 64));
    m = fmaxf(m, __shfl_xor(m, 16, 64));
    m = fmaxf(m, __shfl_xor(m, 32, 64));
    float sum = 0.f;
    for (int j = j0; j < deg; j += 8) {
        int s = csr_src[base + j];
        float el = asrc[s * 8 + h] + ad;
        el = el >= 0.f ? el : NEG_SLOPE * el;
        float p = expf(el - m);
        sum += p;
        aE[(size_t)(base + j) * 8 + h] = p;
    }
    sum += __shfl_xor(sum, 8, 64);
    sum += __shfl_xor(sum, 16, 64);
    sum += __shfl_xor(sum, 32, 64);
    float inv = 1.f / (sum + 1e-16f);
    for (int j = j0; j < deg; j += 8) aE[(size_t)(base + j) * 8 + h] *= inv;
}

// aggregate in x-space: z[d][h][k] = sum_j alpha[j,h] * x[src_j][k]
__global__ __launch_bounds__(512) void k_aggx(
    const int* __restrict__ rs, const int* __restrict__ csr_src,
    const float* __restrict__ aE, const float* __restrict__ x,
    bf16* __restrict__ z, int N)
{
    int d = blockIdx.x;
    int t = threadIdx.x;
    int h = t >> 6, k = t & 63;
    int base = rs[d], end = rs[d + 1];
    float acc = 0.f;
    int p = base;
    for (; p + 3 < end; p += 4) {
        int s0 = csr_src[p],     s1 = csr_src[p + 1];
        int s2 = csr_src[p + 2], s3 = csr_src[p + 3];
        float a0 = aE[(size_t)p * 8 + h];
        float a1 = aE[(size_t)(p + 1) * 8 + h];
        float a2 = aE[(size_t)(p + 2) * 8 + h];
        float a3 = aE[(size_t)(p + 3) * 8 + h];
        float x0 = x[(size_t)s0 * 64 + k];
        float x1 = x[(size_t)s1 * 64 + k];
        float x2 = x[(size_t)s2 * 64 + k];
        float x3 = x[(size_t)s3 * 64 + k];
        acc += a0 * x0 + a1 * x1 + a2 * x2 + a3 * x3;
    }
    for (; p < end; ++p) {
        int s0 = csr_src[p];
        acc += aE[(size_t)p * 8 + h] * x[(size_t)s0 * 64 + k];
    }
    z[(size_t)d * 512 + t] = __float2bfloat16(acc);
}

// per-head GEMM: y[n, h*64+c2] = elu( sum_k z[n][h][k] * W1[k][h*64+c2] + b1 )
// (R4 form: coalesced W1 row loads, b32 broadcast LDS reads — no spills)
#define NPB 8
__global__ __launch_bounds__(512) void k_gemmz(
    const bf16* __restrict__ z, const float* __restrict__ W1,
    const float* __restrict__ b1, bf16* __restrict__ y, int N)
{
    int n0 = blockIdx.x * NPB;
    int t = threadIdx.x;
    __shared__ float zs[NPB][512];
    {
        // thread t loads 8 consecutive bf16 = 16B (fully coalesced)
        int e = t * 8;
        int m = e >> 9, col = e & 511;
        int n = n0 + m;
        if (n < N) {
            ushort8 u = *(const ushort8*)(z + (size_t)n * 512 + col);
#pragma unroll
            for (int j = 0; j < 8; ++j) zs[m][col + j] = bf2f(u[j]);
        } else {
#pragma unroll
            for (int j = 0; j < 8; ++j) zs[m][col + j] = 0.f;
        }
    }
    __syncthreads();
    int h = t >> 6;
    float acc[NPB];
#pragma unroll
    for (int m = 0; m < NPB; ++m) acc[m] = 0.f;
#pragma unroll 8
    for (int k = 0; k < 64; ++k) {
        float w = W1[k * 512 + t];
#pragma unroll
        for (int m = 0; m < NPB; ++m) acc[m] += zs[m][h * 64 + k] * w;
    }
    float bias = b1[t];
#pragma unroll
    for (int m = 0; m < NPB; ++m) {
        int n = n0 + m;
        if (n < N) {
            float v = acc[m] + bias;
            v = v > 0.f ? v : expf(v) - 1.f;
            y[(size_t)n * 512 + t] = __float2bfloat16(v);
        }
    }
}

// ================= Layer 2 =================
// h2 = y @ W2 (+ fused attention dots). 512 thr = 8 waves x 4 nodes x 16 lanes.
// 64 nodes per block (2 passes) to amortize W2 staging; W2t XOR-swizzled.
__global__ __launch_bounds__(512) void k_gemm2(
    const bf16* __restrict__ y, const float* __restrict__ W2,
    const float* __restrict__ a_src2, const float* __restrict__ a_dst2,
    float* __restrict__ h2, float* __restrict__ asrc, float* __restrict__ adst, int N)
{
    __shared__ float W2t[17][512];
    __shared__ float a2s[34];
    int t = threadIdx.x;
    for (int i = t; i < 17 * 512; i += 512) {
        int c = i >> 9, k = i & 511;
        W2t[c][SWZ(k)] = W2[k * 17 + c];
    }
    if (t < 17) a2s[t] = a_src2[t];
    else if (t < 34) a2s[t] = a_dst2[t - 17];
    __syncthreads();

    int wave = t >> 6, lane = t & 63;
    int nsub = lane >> 4, ksub = lane & 15;
    int kx = ksub & 7;

#pragma unroll
    for (int pass = 0; pass < 2; ++pass) {
        int n = blockIdx.x * 64 + pass * 32 + wave * 4 + nsub;
        bool valid = (n < N);

        float yk[32];
        if (valid) {
            const ushort8* yr = (const ushort8*)(y + (size_t)n * 512 + ksub * 32);
#pragma unroll
            for (int v = 0; v < 4; ++v) {
                ushort8 u = yr[v];
#pragma unroll
                for (int j = 0; j < 8; ++j) yk[v * 8 + j] = bf2f(u[j]);
            }
        } else {
#pragma unroll
            for (int i = 0; i < 32; ++i) yk[i] = 0.f;
        }

        float acc[17];
#pragma unroll
        for (int c = 0; c < 17; ++c) {
            float a = 0.f;
#pragma unroll
            for (int v = 0; v < 8; ++v) {
                // physical chunk (v ^ kx) holds logical k-chunk v
                const float4 w = *(const float4*)&W2t[c][ksub * 32 + ((v ^ kx) << 2)];
                a += yk[v * 4 + 0] * w.x + yk[v * 4 + 1] * w.y
                   + yk[v * 4 + 2] * w.z + yk[v * 4 + 3] * w.w;
            }
            acc[c] = a;
        }
#pragma unroll
        for (int c = 0; c < 17; ++c) {
            acc[c] += __shfl_xor(acc[c], 1, 16);
            acc[c] += __shfl_xor(acc[c], 2, 16);
            acc[c] += __shfl_xor(acc[c], 4, 16);
            acc[c] += __shfl_xor(acc[c], 8, 16);
        }
        if (valid) {
            if (ksub < 16) h2[(size_t)n * 17 + ksub] = acc[ksub];
            if (ksub == 0) h2[(size_t)n * 17 + 16] = acc[16];
            if (ksub == 1) {
                float s = 0.f;
#pragma unroll
                for (int c = 0; c < 17; ++c) s += acc[c] * a2s[c];
                asrc[n] = s;
            }
            if (ksub == 2) {
                float d = 0.f;
#pragma unroll
                for (int c = 0; c < 17; ++c) d += acc[c] * a2s[17 + c];
                adst[n] = d;
            }
        }
    }
}

// softmax layer2: wave per node, lane = edge slot
__global__ __launch_bounds__(256) void k_sm2(
    const int* __restrict__ rs, const int* __restrict__ csr_src,
    const float* __restrict__ asrc, const float* __restrict__ adst,
    float* __restrict__ alpha, int N)
{
    int node = blockIdx.x * 4 + (threadIdx.x >> 6);
    if (node >= N) return;
    int lane = threadIdx.x & 63;
    int base = rs[node], deg = rs[node + 1] - base;
    float ad = adst[node];
    float m = -1e30f;
    for (int j = lane; j < deg; j += 64) {
        float el = asrc[csr_src[base + j]] + ad;
        el = el >= 0.f ? el : NEG_SLOPE * el;
        m = fmaxf(m, el);
    }
#pragma unroll
    for (int off = 1; off < 64; off <<= 1) m = fmaxf(m, __shfl_xor(m, off, 64));
    float sum = 0.f;
    for (int j = lane; j < deg; j += 64) {
        float el = asrc[csr_src[base + j]] + ad;
        el = el >= 0.f ? el : NEG_SLOPE * el;
        float p = expf(el - m);
        sum += p;
        alpha[base + j] = p;
    }
#pragma unroll
    for (int off = 1; off < 64; off <<= 1) sum += __shfl_xor(sum, off, 64);
    float inv = 1.f / (sum + 1e-16f);
    for (int j = lane; j < deg; j += 64) alpha[base + j] *= inv;
}

// aggregate layer2 + bias + log_softmax: wave per node; lane = (jsub = lane>>5, c = lane&31)
__global__ __launch_bounds__(256) void k_out(
    const int* __restrict__ rs, const int* __restrict__ csr_src,
    const float* __restrict__ alpha, const float* __restrict__ h2,
    const float* __restrict__ b2, float* __restrict__ out, int N)
{
    int node = blockIdx.x * 4 + (threadIdx.x >> 6);
    if (node >= N) return;
    int lane = threadIdx.x & 63;
    int c = lane & 31, jsub = lane >> 5;
    int base = rs[node], end = rs[node + 1];
    float acc = 0.f;
    if (c < 17) {
        for (int p = base + jsub; p < end; p += 2) {
            int s = csr_src[p];
            acc += alpha[p] * h2[(size_t)s * 17 + c];
        }
    }
    acc += __shfl_xor(acc, 32, 64);  // combine the two edge halves
    float logit = (c < 17) ? acc + b2[c] : -1e30f;
    float m = logit;
#pragma unroll
    for (int off = 1; off < 32; off <<= 1) m = fmaxf(m, __shfl_xor(m, off, 32));
    float p = (c < 17) ? expf(logit - m) : 0.f;
    float ssum = p;
#pragma unroll
    for (int off = 1; off < 32; off <<= 1) ssum += __shfl_xor(ssum, off, 32);
    if (c < 17 && jsub == 0) out[(size_t)node * 17 + c] = logit - m - logf(ssum);
}

extern "C" void kernel_launch(void* const* d_in, const int* in_sizes, int n_in,
                              void* d_out, int out_size, void* d_ws, size_t ws_size,
                              hipStream_t stream)
{
    const float* x      = (const float*)d_in[0];
    const int*   ei     = (const int*)d_in[1];
    const float* W1     = (const float*)d_in[2];
    const float* asrc1w = (const float*)d_in[3];
    const float* adst1w = (const float*)d_in[4];
    const float* b1     = (const float*)d_in[5];
    const float* W2     = (const float*)d_in[6];
    const float* asrc2w = (const float*)d_in[7];
    const float* adst2w = (const float*)d_in[8];
    const float* b2     = (const float*)d_in[9];
    float* out = (float*)d_out;

    const int N = in_sizes[0] / 64;
    const int E = in_sizes[1] / 2;
    const int Etot = N + E;

    // workspace layout
    float* ws = (float*)d_ws;
    size_t o = 0;
    bf16*  z     = (bf16*)(ws + o); o += (size_t)N * 256;   // N*512 bf16
    bf16*  y     = (bf16*)(ws + o); o += (size_t)N * 256;   // N*512 bf16
    float* wboth = ws + o; o += 1024;
    float* asrc1 = ws + o; o += (size_t)N * 8;
    float* adst1 = ws + o; o += (size_t)N * 8;
    float* aE1   = ws + o; o += (size_t)Etot * 8;
    float* h2    = ws + o; o += (size_t)N * 17;
    float* asrc2 = ws + o; o += (size_t)N;
    float* adst2 = ws + o; o += (size_t)N;
    float* aE2   = ws + o; o += (size_t)Etot;
    int* deg     = (int*)(ws + o); o += (size_t)N;
    int* cur     = (int*)(ws + o); o += (size_t)N;
    int* rs      = (int*)(ws + o); o += (size_t)N + 1;
    int* csr_src = (int*)(ws + o); o += (size_t)Etot;

    hipMemsetAsync(deg, 0, (size_t)N * 4, stream);
    hipMemsetAsync(cur, 0, (size_t)N * 4, stream);

    // CSR build
    {
        int blk = 256, g = (Etot + blk - 1) / blk;
        k_hist<<<g, blk, 0, stream>>>(ei, E, Etot, deg);
        k_scan<<<1, 1024, 0, stream>>>(deg, rs, N);
        k_fill<<<g, blk, 0, stream>>>(ei, E, Etot, rs, cur, csr_src);
    }

    // layer 1
    k_prew<<<1, 512, 0, stream>>>(W1, asrc1w, adst1w, wboth);
    k_alpha1n<<<(N + 15) / 16, 256, 0, stream>>>(x, wboth, asrc1, adst1, N);
    k_sm1<<<(N + 3) / 4, 256, 0, stream>>>(rs, csr_src, asrc1, adst1, aE1, N);
    k_aggx<<<N, 512, 0, stream>>>(rs, csr_src, aE1, x, z, N);
    k_gemmz<<<(N + NPB - 1) / NPB, 512, 0, stream>>>(z, W1, b1, y, N);

    // layer 2
    k_gemm2<<<(N + 63) / 64, 512, 0, stream>>>(y, W2, asrc2w, adst2w, h2, asrc2, adst2, N);
    k_sm2<<<(N + 3) / 4, 256, 0, stream>>>(rs, csr_src, asrc2, adst2, aE2, N);
    k_out<<<(N + 3) / 4, 256, 0, stream>>>(rs, csr_src, aE2, h2, b2, out, N);
}

// Round 7
// 424.645 us; speedup vs baseline: 3.7852x; 1.2081x over previous
//
#include <hip/hip_runtime.h>
#include <hip/hip_bf16.h>
#include <math.h>

#define NEG_SLOPE 0.2f
typedef __hip_bfloat16 bf16;
typedef __attribute__((ext_vector_type(8))) unsigned short ushort8;

// XOR swizzle: logical float-column c -> physical column (breaks stride-32 conflicts)
#define SWZ(c) ((c) ^ ((((c) >> 5) & 7) << 2))

__device__ __forceinline__ float bf2f(unsigned short u) {
    return __uint_as_float(((unsigned)u) << 16);
}

__device__ __forceinline__ void edge_sd(const int* __restrict__ ei, int E, int e, int& s, int& d) {
    if (e < E) { s = ei[e]; d = ei[E + e]; }
    else { s = e - E; d = s; }  // self-loop
}

// ================= CSR build =================
__global__ void k_hist(const int* __restrict__ ei, int E, int Etot, int* __restrict__ deg)
{
    int e = blockIdx.x * blockDim.x + threadIdx.x;
    if (e >= Etot) return;
    int s, d; edge_sd(ei, E, e, s, d);
    atomicAdd(&deg[d], 1);
}

__global__ __launch_bounds__(1024) void k_scan(const int* __restrict__ deg,
                                               int* __restrict__ rs, int N)
{
    __shared__ int part[1024];
    int t = threadIdx.x;
    int chunk = (N + 1023) >> 10;
    int b = t * chunk, e = min(b + chunk, N);
    int s = 0;
    for (int i = b; i < e; ++i) s += deg[i];
    part[t] = s;
    __syncthreads();
    for (int off = 1; off < 1024; off <<= 1) {
        int v = (t >= off) ? part[t - off] : 0;
        __syncthreads();
        part[t] += v;
        __syncthreads();
    }
    int excl = (t == 0) ? 0 : part[t - 1];
    for (int i = b; i < e; ++i) { rs[i] = excl; excl += deg[i]; }
    if (t == 1023) rs[N] = part[1023];
}

__global__ void k_fill(const int* __restrict__ ei, int E, int Etot,
                       const int* __restrict__ rs, int* __restrict__ cur,
                       int* __restrict__ csr_src)
{
    int e = blockIdx.x * blockDim.x + threadIdx.x;
    if (e >= Etot) return;
    int s, d; edge_sd(ei, E, e, s, d);
    int pos = rs[d] + atomicAdd(&cur[d], 1);
    csr_src[pos] = s;
}

// ================= Layer 1 =================
// wboth[k][c16]: c<8 -> src-fold head c ; c>=8 -> dst-fold head c-8
__global__ __launch_bounds__(512) void k_prew(
    const float* __restrict__ W1, const float* __restrict__ a_src,
    const float* __restrict__ a_dst, float* __restrict__ wboth)
{
    int t = threadIdx.x;           // 512 = 64 k x 8 h
    int k = t >> 3, h = t & 7;
    float s = 0.f, d = 0.f;
    const float* wr = W1 + k * 512 + h * 64;
    const float* as = a_src + h * 64;
    const float* ad = a_dst + h * 64;
#pragma unroll
    for (int c = 0; c < 64; ++c) { s += wr[c] * as[c]; d += wr[c] * ad[c]; }
    wboth[k * 16 + h] = s;
    wboth[k * 16 + 8 + h] = d;
}

// per-node attention terms: 256 thr = 4 waves x 4 nodes x 16 lanes
__global__ __launch_bounds__(256) void k_alpha1n(
    const float* __restrict__ x, const float* __restrict__ wboth,
    float* __restrict__ asrc, float* __restrict__ adst, int N)
{
    __shared__ float wl[16][64];   // transposed: wl[c][k]
    int t = threadIdx.x;
    for (int i = t; i < 1024; i += 256) {
        int k = i >> 4, c = i & 15;
        wl[c][k] = wboth[i];
    }
    __syncthreads();
    int wave = t >> 6, lane = t & 63;
    int nsub = lane >> 4, ksub = lane & 15;
    int n = blockIdx.x * 16 + wave * 4 + nsub;
    bool valid = (n < N);
    float xv[4];
#pragma unroll
    for (int i = 0; i < 4; ++i)
        xv[i] = valid ? x[(size_t)n * 64 + i * 16 + ksub] : 0.f;
    float acc[16];
#pragma unroll
    for (int c = 0; c < 16; ++c) acc[c] = 0.f;
#pragma unroll
    for (int i = 0; i < 4; ++i) {
        float xi = xv[i];
        int k = i * 16 + ksub;
#pragma unroll
        for (int c = 0; c < 16; ++c) acc[c] += xi * wl[c][k];
    }
#pragma unroll
    for (int c = 0; c < 16; ++c) {
        acc[c] += __shfl_xor(acc[c], 1, 16);
        acc[c] += __shfl_xor(acc[c], 2, 16);
        acc[c] += __shfl_xor(acc[c], 4, 16);
        acc[c] += __shfl_xor(acc[c], 8, 16);
    }
    if (valid) {
        if (ksub < 8) asrc[n * 8 + ksub] = acc[ksub];
        else          adst[n * 8 + (ksub - 8)] = acc[ksub];
    }
}

// softmax layer1: wave per node; lane = (j0 = lane>>3, head = lane&7)
__global__ __launch_bounds__(256) void k_sm1(
    const int* __restrict__ rs, const int* __restrict__ csr_src,
    const float* __restrict__ asrc, const float* __restrict__ adst,
    float* __restrict__ aE, int N)
{
    int node = blockIdx.x * 4 + (threadIdx.x >> 6);
    if (node >= N) return;
    int lane = threadIdx.x & 63;
    int h = lane & 7, j0 = lane >> 3;
    int base = rs[node], deg = rs[node + 1] - base;
    float ad = adst[node * 8 + h];
    float m = -1e30f;
    for (int j = j0; j < deg; j += 8) {
        int s = csr_src[base + j];
        float el = asrc[s * 8 + h] + ad;
        el = el >= 0.f ? el : NEG_SLOPE * el;
        m = fmaxf(m, el);
    }
    m = fmaxf(m, __shfl_xor(m, 8, 64));
    m = fmaxf(m, __shfl_xor(m, 16, 64));
    m = fmaxf(m, __shfl_xor(m, 32, 64));
    float sum = 0.f;
    for (int j = j0; j < deg; j += 8) {
        int s = csr_src[base + j];
        float el = asrc[s * 8 + h] + ad;
        el = el >= 0.f ? el : NEG_SLOPE * el;
        float p = expf(el - m);
        sum += p;
        aE[(size_t)(base + j) * 8 + h] = p;
    }
    sum += __shfl_xor(sum, 8, 64);
    sum += __shfl_xor(sum, 16, 64);
    sum += __shfl_xor(sum, 32, 64);
    float inv = 1.f / (sum + 1e-16f);
    for (int j = j0; j < deg; j += 8) aE[(size_t)(base + j) * 8 + h] *= inv;
}

// ===== fused: x-space aggregate (wave per node) + per-head GEMM + bias + ELU =====
// phase 1: wave m handles node n0+m; lane = k; acc[8] = all heads.
//   edge indices: one coalesced 64-wide load, broadcast via __shfl.
//   z staged in LDS with pad-9 stride (9k mod 32 bijective -> conflict-free).
// phase 2: R4-proven gemmz body; thread t = output col (h = t>>6); zs broadcast b32.
#define NPB 8
__global__ __launch_bounds__(512) void k_agg_gemm1(
    const int* __restrict__ rs, const int* __restrict__ csr_src,
    const float* __restrict__ aE, const float* __restrict__ x,
    const float* __restrict__ W1, const float* __restrict__ b1,
    bf16* __restrict__ y, int N)
{
    __shared__ float zs[NPB][64 * 9];   // 18 KB
    int t = threadIdx.x;
    int wave = t >> 6, lane = t & 63;
    int n = blockIdx.x * NPB + wave;

    if (n < N) {
        int base = rs[n], deg = rs[n + 1] - base;
        float acc[8];
#pragma unroll
        for (int h = 0; h < 8; ++h) acc[h] = 0.f;
        for (int j0 = 0; j0 < deg; j0 += 64) {
            int cnt = min(64, deg - j0);
            int sidx = csr_src[base + j0 + min(lane, cnt - 1)];
#pragma unroll 2
            for (int j = 0; j < cnt; ++j) {
                int s = __shfl(sidx, j, 64);
                float xv = x[(size_t)s * 64 + lane];
                const float4* ap = (const float4*)(aE + (size_t)(base + j0 + j) * 8);
                float4 a0 = ap[0], a1 = ap[1];
                acc[0] += a0.x * xv; acc[1] += a0.y * xv;
                acc[2] += a0.z * xv; acc[3] += a0.w * xv;
                acc[4] += a1.x * xv; acc[5] += a1.y * xv;
                acc[6] += a1.z * xv; acc[7] += a1.w * xv;
            }
        }
#pragma unroll
        for (int h = 0; h < 8; ++h) zs[wave][lane * 9 + h] = acc[h];
    } else {
#pragma unroll
        for (int h = 0; h < 8; ++h) zs[wave][lane * 9 + h] = 0.f;
    }
    __syncthreads();

    // phase 2: y[n, t] = elu( sum_k zs[m][k*9 + (t>>6)] * W1[k*512 + t] + b1[t] )
    int n0 = blockIdx.x * NPB;
    int h = t >> 6;
    float acc2[NPB];
#pragma unroll
    for (int m = 0; m < NPB; ++m) acc2[m] = 0.f;
#pragma unroll 8
    for (int k = 0; k < 64; ++k) {
        float w = W1[k * 512 + t];
#pragma unroll
        for (int m = 0; m < NPB; ++m) acc2[m] += zs[m][k * 9 + h] * w;
    }
    float bias = b1[t];
#pragma unroll
    for (int m = 0; m < NPB; ++m) {
        int nn = n0 + m;
        if (nn < N) {
            float v = acc2[m] + bias;
            v = v > 0.f ? v : expf(v) - 1.f;
            y[(size_t)nn * 512 + t] = __float2bfloat16(v);
        }
    }
}

// ================= Layer 2 =================
// h2 = y @ W2 (+ fused attention dots). 512 thr = 8 waves x 4 nodes x 16 lanes.
// 64 nodes per block (2 passes) to amortize W2 staging; W2t XOR-swizzled.
__global__ __launch_bounds__(512) void k_gemm2(
    const bf16* __restrict__ y, const float* __restrict__ W2,
    const float* __restrict__ a_src2, const float* __restrict__ a_dst2,
    float* __restrict__ h2, float* __restrict__ asrc, float* __restrict__ adst, int N)
{
    __shared__ float W2t[17][512];
    __shared__ float a2s[34];
    int t = threadIdx.x;
    for (int i = t; i < 17 * 512; i += 512) {
        int c = i >> 9, k = i & 511;
        W2t[c][SWZ(k)] = W2[k * 17 + c];
    }
    if (t < 17) a2s[t] = a_src2[t];
    else if (t < 34) a2s[t] = a_dst2[t - 17];
    __syncthreads();

    int wave = t >> 6, lane = t & 63;
    int nsub = lane >> 4, ksub = lane & 15;
    int kx = ksub & 7;

#pragma unroll
    for (int pass = 0; pass < 2; ++pass) {
        int n = blockIdx.x * 64 + pass * 32 + wave * 4 + nsub;
        bool valid = (n < N);

        float yk[32];
        if (valid) {
            const ushort8* yr = (const ushort8*)(y + (size_t)n * 512 + ksub * 32);
#pragma unroll
            for (int v = 0; v < 4; ++v) {
                ushort8 u = yr[v];
#pragma unroll
                for (int j = 0; j < 8; ++j) yk[v * 8 + j] = bf2f(u[j]);
            }
        } else {
#pragma unroll
            for (int i = 0; i < 32; ++i) yk[i] = 0.f;
        }

        float acc[17];
#pragma unroll
        for (int c = 0; c < 17; ++c) {
            float a = 0.f;
#pragma unroll
            for (int v = 0; v < 8; ++v) {
                // physical chunk (v ^ kx) holds logical k-chunk v
                const float4 w = *(const float4*)&W2t[c][ksub * 32 + ((v ^ kx) << 2)];
                a += yk[v * 4 + 0] * w.x + yk[v * 4 + 1] * w.y
                   + yk[v * 4 + 2] * w.z + yk[v * 4 + 3] * w.w;
            }
            acc[c] = a;
        }
#pragma unroll
        for (int c = 0; c < 17; ++c) {
            acc[c] += __shfl_xor(acc[c], 1, 16);
            acc[c] += __shfl_xor(acc[c], 2, 16);
            acc[c] += __shfl_xor(acc[c], 4, 16);
            acc[c] += __shfl_xor(acc[c], 8, 16);
        }
        if (valid) {
            if (ksub < 16) h2[(size_t)n * 17 + ksub] = acc[ksub];
            if (ksub == 0) h2[(size_t)n * 17 + 16] = acc[16];
            if (ksub == 1) {
                float s = 0.f;
#pragma unroll
                for (int c = 0; c < 17; ++c) s += acc[c] * a2s[c];
                asrc[n] = s;
            }
            if (ksub == 2) {
                float d = 0.f;
#pragma unroll
                for (int c = 0; c < 17; ++c) d += acc[c] * a2s[17 + c];
                adst[n] = d;
            }
        }
    }
}

// softmax layer2: wave per node, lane = edge slot
__global__ __launch_bounds__(256) void k_sm2(
    const int* __restrict__ rs, const int* __restrict__ csr_src,
    const float* __restrict__ asrc, const float* __restrict__ adst,
    float* __restrict__ alpha, int N)
{
    int node = blockIdx.x * 4 + (threadIdx.x >> 6);
    if (node >= N) return;
    int lane = threadIdx.x & 63;
    int base = rs[node], deg = rs[node + 1] - base;
    float ad = adst[node];
    float m = -1e30f;
    for (int j = lane; j < deg; j += 64) {
        float el = asrc[csr_src[base + j]] + ad;
        el = el >= 0.f ? el : NEG_SLOPE * el;
        m = fmaxf(m, el);
    }
#pragma unroll
    for (int off = 1; off < 64; off <<= 1) m = fmaxf(m, __shfl_xor(m, off, 64));
    float sum = 0.f;
    for (int j = lane; j < deg; j += 64) {
        float el = asrc[csr_src[base + j]] + ad;
        el = el >= 0.f ? el : NEG_SLOPE * el;
        float p = expf(el - m);
        sum += p;
        alpha[base + j] = p;
    }
#pragma unroll
    for (int off = 1; off < 64; off <<= 1) sum += __shfl_xor(sum, off, 64);
    float inv = 1.f / (sum + 1e-16f);
    for (int j = lane; j < deg; j += 64) alpha[base + j] *= inv;
}

// aggregate layer2 + bias + log_softmax: wave per node; lane = (jsub = lane>>5, c = lane&31)
__global__ __launch_bounds__(256) void k_out(
    const int* __restrict__ rs, const int* __restrict__ csr_src,
    const float* __restrict__ alpha, const float* __restrict__ h2,
    const float* __restrict__ b2, float* __restrict__ out, int N)
{
    int node = blockIdx.x * 4 + (threadIdx.x >> 6);
    if (node >= N) return;
    int lane = threadIdx.x & 63;
    int c = lane & 31, jsub = lane >> 5;
    int base = rs[node], end = rs[node + 1];
    float acc = 0.f;
    if (c < 17) {
        for (int p = base + jsub; p < end; p += 2) {
            int s = csr_src[p];
            acc += alpha[p] * h2[(size_t)s * 17 + c];
        }
    }
    acc += __shfl_xor(acc, 32, 64);  // combine the two edge halves
    float logit = (c < 17) ? acc + b2[c] : -1e30f;
    float m = logit;
#pragma unroll
    for (int off = 1; off < 32; off <<= 1) m = fmaxf(m, __shfl_xor(m, off, 32));
    float p = (c < 17) ? expf(logit - m) : 0.f;
    float ssum = p;
#pragma unroll
    for (int off = 1; off < 32; off <<= 1) ssum += __shfl_xor(ssum, off, 32);
    if (c < 17 && jsub == 0) out[(size_t)node * 17 + c] = logit - m - logf(ssum);
}

extern "C" void kernel_launch(void* const* d_in, const int* in_sizes, int n_in,
                              void* d_out, int out_size, void* d_ws, size_t ws_size,
                              hipStream_t stream)
{
    const float* x      = (const float*)d_in[0];
    const int*   ei     = (const int*)d_in[1];
    const float* W1     = (const float*)d_in[2];
    const float* asrc1w = (const float*)d_in[3];
    const float* adst1w = (const float*)d_in[4];
    const float* b1     = (const float*)d_in[5];
    const float* W2     = (const float*)d_in[6];
    const float* asrc2w = (const float*)d_in[7];
    const float* adst2w = (const float*)d_in[8];
    const float* b2     = (const float*)d_in[9];
    float* out = (float*)d_out;

    const int N = in_sizes[0] / 64;
    const int E = in_sizes[1] / 2;
    const int Etot = N + E;

    // workspace layout
    float* ws = (float*)d_ws;
    size_t o = 0;
    bf16*  y     = (bf16*)(ws + o); o += (size_t)N * 256;   // N*512 bf16
    float* wboth = ws + o; o += 1024;
    float* asrc1 = ws + o; o += (size_t)N * 8;
    float* adst1 = ws + o; o += (size_t)N * 8;
    float* aE1   = ws + o; o += (size_t)Etot * 8;
    float* h2    = ws + o; o += (size_t)N * 17;
    float* asrc2 = ws + o; o += (size_t)N;
    float* adst2 = ws + o; o += (size_t)N;
    float* aE2   = ws + o; o += (size_t)Etot;
    int* deg     = (int*)(ws + o); o += (size_t)N;
    int* cur     = (int*)(ws + o); o += (size_t)N;
    int* rs      = (int*)(ws + o); o += (size_t)N + 1;
    int* csr_src = (int*)(ws + o); o += (size_t)Etot;

    hipMemsetAsync(deg, 0, (size_t)N * 4, stream);
    hipMemsetAsync(cur, 0, (size_t)N * 4, stream);

    // CSR build
    {
        int blk = 256, g = (Etot + blk - 1) / blk;
        k_hist<<<g, blk, 0, stream>>>(ei, E, Etot, deg);
        k_scan<<<1, 1024, 0, stream>>>(deg, rs, N);
        k_fill<<<g, blk, 0, stream>>>(ei, E, Etot, rs, cur, csr_src);
    }

    // layer 1
    k_prew<<<1, 512, 0, stream>>>(W1, asrc1w, adst1w, wboth);
    k_alpha1n<<<(N + 15) / 16, 256, 0, stream>>>(x, wboth, asrc1, adst1, N);
    k_sm1<<<(N + 3) / 4, 256, 0, stream>>>(rs, csr_src, asrc1, adst1, aE1, N);
    k_agg_gemm1<<<(N + NPB - 1) / NPB, 512, 0, stream>>>(rs, csr_src, aE1, x, W1, b1, y, N);

    // layer 2
    k_gemm2<<<(N + 63) / 64, 512, 0, stream>>>(y, W2, asrc2w, adst2w, h2, asrc2, adst2, N);
    k_sm2<<<(N + 3) / 4, 256, 0, stream>>>(rs, csr_src, asrc2, adst2, aE2, N);
    k_out<<<(N + 3) / 4, 256, 0, stream>>>(rs, csr_src, aE2, h2, b2, out, N);
}